// Round 2
// 195.665 us; speedup vs baseline: 1.0096x; 1.0096x over previous
//
#include <hip/hip_runtime.h>
#include <math.h>

// GNN_2826088481036 — R6: R4's proven bit-ops RNE pack everywhere (R5's
// v_cvt_pk_bf16_f32 asm mis-rounded/swapped on this toolchain -> absmax 1.67).
// New in R6:
//  * one-block prep kernel hoists the B-frag hi/lo split (weights-only work,
//    ~550 VALU ops/lane x 15625 waves in R4) into a 12.4KB table in d_ws.
//    Main kernel: 12 L2-hot dwordx4 loads/lane instead.
//  * layer-1 computes (p, p+16) pairs and packs on the fly (no u[32] array,
//    -32 VGPRs); launch_bounds stays (256,3) — if regs land <=128 the HW
//    gives 4 waves/SIMD for free, no forced spill.

#define BLK 256
#define RS  20   // LDS row stride (dwords): mult of 4 (16B rows), 20%32 spreads banks

#define LOG2E 1.44269504088896340736f
#define LN2   0.69314718055994530942f

using short8 = __attribute__((ext_vector_type(8))) short;  // 8 bf16 A/B frag
using f32x4  = __attribute__((ext_vector_type(4))) float;  // C/D frag

__device__ __forceinline__ short8 as_s8(uint4 u) { return __builtin_bit_cast(short8, u); }

// RNE bf16 of a float, as low 16 bits (inputs here are never NaN)
__device__ __forceinline__ unsigned bf16_rne(float a) {
    unsigned u = __float_as_uint(a);
    return (u + 0x7fffu + ((u >> 16) & 1u)) >> 16;
}
__device__ __forceinline__ unsigned pack_bf16x2(float lo, float hi) {
    return bf16_rne(lo) | (bf16_rne(hi) << 16);
}

// u = log2(1 + 2^t)  ==  log2e * softplus(t/log2e); 3 instr, 2 transcendental
__device__ __forceinline__ float softplus_log2(float t) {
    return __builtin_amdgcn_logf(1.0f + __builtin_amdgcn_exp2f(t));
}

// ---- ws layout (dwords) ----
// [0, 3072)    : B-frag tables, uint4 index ((L*2+nt)*2 + h)*64 + lane, h=0 hi, h=1 lo
// [3072, 3168) : LOG2E * bL[f]   at 3072 + L*32 + f
// [3168]       : s_lin_ln2 = (linW[0]+linW[1]+linW[2]) * LN2
// [3169]       : lb = linb[0]
#define WS_DWORDS 3172
#define WS_BYTES  (WS_DWORDS * 4)

__global__ void gnn_prep(
    const float* __restrict__ W2, const float* __restrict__ b2,
    const float* __restrict__ W3, const float* __restrict__ b3,
    const float* __restrict__ W4, const float* __restrict__ b4,
    const float* __restrict__ linW, const float* __restrict__ linb,
    unsigned* __restrict__ ws)
{
    const int t = threadIdx.x;                 // 384 threads, 1 block
    const float* Ws[3] = { W2, W3, W4 };
    const float* bs[3] = { b2, b3, b4 };

    if (t < 384) {
        const int L    = t >> 7;               // layer 0..2
        const int nt   = (t >> 6) & 1;
        const int lane = t & 63;
        const int q    = lane >> 4;
        const int l16  = lane & 15;
        const float* __restrict__ W = Ws[L];
        unsigned hid[4], lod[4];
        #pragma unroll
        for (int d = 0; d < 4; ++d) {
            // permuted K: kappa=2d+e (+q*8) -> feature (q*4+d) + 16*e
            float w0 = W[(q * 4 + d) * 32      + nt * 16 + l16];
            float w1 = W[(q * 4 + d + 16) * 32 + nt * 16 + l16];
            unsigned h0 = bf16_rne(w0), h1 = bf16_rne(w1);
            float w0h = __uint_as_float(h0 << 16);
            float w1h = __uint_as_float(h1 << 16);
            hid[d] = h0 | (h1 << 16);
            lod[d] = pack_bf16x2(w0 - w0h, w1 - w1h);
        }
        uint4* o = (uint4*)ws;
        o[((L * 2 + nt) * 2 + 0) * 64 + lane] = make_uint4(hid[0], hid[1], hid[2], hid[3]);
        o[((L * 2 + nt) * 2 + 1) * 64 + lane] = make_uint4(lod[0], lod[1], lod[2], lod[3]);
    }
    if (t < 96) {
        const int L = t >> 5, f = t & 31;
        ((float*)ws)[3072 + t] = LOG2E * bs[L][f];
    }
    if (t == 96) ((float*)ws)[3168] = (linW[0] + linW[1] + linW[2]) * LN2;
    if (t == 97) ((float*)ws)[3169] = linb[0];
}

template<bool USE_WS>
__global__ __launch_bounds__(BLK, 3) void gnn_mfma6(
    const float* __restrict__ x,
    const float* __restrict__ W1, const float* __restrict__ b1,
    const float* __restrict__ W2, const float* __restrict__ b2,
    const float* __restrict__ W3, const float* __restrict__ b3,
    const float* __restrict__ W4, const float* __restrict__ b4,
    const float* __restrict__ linW, const float* __restrict__ linb,
    const unsigned* __restrict__ ws,
    float* __restrict__ out, int nB)
{
    __shared__ unsigned lds[4 * 64 * RS];          // 20,480 B

    const int tid  = threadIdx.x;
    const int wid  = tid >> 6;
    const int lane = tid & 63;
    const int q    = lane >> 4;    // k-chunk selector (A/B), row-quad (C)
    const int l16  = lane & 15;    // row (A) / col (B,C)

    unsigned* myLds = lds + wid * (64 * RS);
    const int sbase = blockIdx.x * BLK + wid * 64;

    // ---------------- layer 1 (K=4, VALU, t-domain) ----------------
    const int b0 = sbase + lane;
    float xm0 = 0.f, xm1 = 0.f, xm2 = 0.f, xm3 = 0.f;
    if (b0 < nB) {
        const float4* xp = (const float4*)(x + (size_t)b0 * 12);
        float4 n0 = xp[0], n1 = xp[1], n2 = xp[2];
        const float k = LOG2E / 3.0f;              // fold mean and log2e
        xm0 = (n0.x + n1.x + n2.x) * k;
        xm1 = (n0.y + n1.y + n2.y) * k;
        xm2 = (n0.z + n1.z + n2.z) * k;
        xm3 = (n0.w + n1.w + n2.w) * k;
    }
    {
        // own row: dword p = [sp(feat p+16) | sp(feat p)]; pack pair on the fly
        uint4* rowp = (uint4*)(myLds + lane * RS);
        #pragma unroll
        for (int d = 0; d < 4; ++d) {
            uint4 row;
            #pragma unroll
            for (int j = 0; j < 4; ++j) {
                const int f = 4 * d + j;
                float t0 = LOG2E * b1[f];                 // uniform -> scalar pipe
                t0 = fmaf(xm0, W1[f],       t0);
                t0 = fmaf(xm1, W1[32 + f],  t0);
                t0 = fmaf(xm2, W1[64 + f],  t0);
                t0 = fmaf(xm3, W1[96 + f],  t0);
                float t1 = LOG2E * b1[16 + f];
                t1 = fmaf(xm0, W1[16 + f],  t1);
                t1 = fmaf(xm1, W1[48 + f],  t1);
                t1 = fmaf(xm2, W1[80 + f],  t1);
                t1 = fmaf(xm3, W1[112 + f], t1);
                (&row.x)[j] = pack_bf16x2(softplus_log2(t0), softplus_log2(t1));
            }
            rowp[d] = row;
        }
    }

    const float* Ws[3] = { W2, W3, W4 };
    const float* bs[3] = { b2, b3, b4 };

    float s_lin_ln2, lb;
    if constexpr (USE_WS) {
        s_lin_ln2 = ((const float*)ws)[3168];
        lb        = ((const float*)ws)[3169];
    } else {
        s_lin_ln2 = (linW[0] + linW[1] + linW[2]) * LN2;
        lb        = linb[0];
    }

    // ---------------- layers 2..4 via MFMA ----------------
    #pragma unroll
    for (int layer = 0; layer < 3; ++layer) {
        // B frags, permuted K: kappa=2d+e (+q*8) -> feature (q*4+d) + 16*e
        uint4 bhi[2], blo[2];
        float bias0, bias1;
        if constexpr (USE_WS) {
            const uint4* wtab = (const uint4*)ws;
            #pragma unroll
            for (int nt = 0; nt < 2; ++nt) {
                bhi[nt] = wtab[((layer * 2 + nt) * 2 + 0) * 64 + lane];
                blo[nt] = wtab[((layer * 2 + nt) * 2 + 1) * 64 + lane];
            }
            bias0 = ((const float*)ws)[3072 + layer * 32 + l16];
            bias1 = ((const float*)ws)[3072 + layer * 32 + 16 + l16];
        } else {
            const float* __restrict__ W  = Ws[layer];
            const float* __restrict__ bL = bs[layer];
            #pragma unroll
            for (int nt = 0; nt < 2; ++nt) {
                #pragma unroll
                for (int d = 0; d < 4; ++d) {
                    float w0 = W[(q * 4 + d) * 32      + nt * 16 + l16];
                    float w1 = W[(q * 4 + d + 16) * 32 + nt * 16 + l16];
                    unsigned h0 = bf16_rne(w0), h1 = bf16_rne(w1);
                    float w0h = __uint_as_float(h0 << 16);
                    float w1h = __uint_as_float(h1 << 16);
                    (&bhi[nt].x)[d] = h0 | (h1 << 16);
                    (&blo[nt].x)[d] = pack_bf16x2(w0 - w0h, w1 - w1h);
                }
            }
            bias0 = LOG2E * bL[l16];
            bias1 = LOG2E * bL[16 + l16];
        }

        // A frags: one aligned ds_read_b128 per mt (row mt*16+l16, dwords q*4..q*4+3)
        uint4 afr[4];
        #pragma unroll
        for (int mt = 0; mt < 4; ++mt)
            afr[mt] = *(const uint4*)(myLds + (mt * 16 + l16) * RS + q * 4);

        // 16 MFMAs: acc = A*Bhi + A*Blo
        f32x4 acc[4][2];
        #pragma unroll
        for (int mt = 0; mt < 4; ++mt)
            #pragma unroll
            for (int nt = 0; nt < 2; ++nt) {
                f32x4 c = { 0.f, 0.f, 0.f, 0.f };
                c = __builtin_amdgcn_mfma_f32_16x16x32_bf16(as_s8(afr[mt]), as_s8(blo[nt]), c, 0, 0, 0);
                c = __builtin_amdgcn_mfma_f32_16x16x32_bf16(as_s8(afr[mt]), as_s8(bhi[nt]), c, 0, 0, 0);
                acc[mt][nt] = c;
            }

        if (layer < 2) {
            // softplus + pack pair (cols l16 / l16+16) + one ds_write per (mt,r)
            #pragma unroll
            for (int mt = 0; mt < 4; ++mt)
                #pragma unroll
                for (int r = 0; r < 4; ++r) {
                    float v0 = softplus_log2(acc[mt][0][r] + bias0);
                    float v1 = softplus_log2(acc[mt][1][r] + bias1);
                    myLds[(mt * 16 + q * 4 + r) * RS + l16] = pack_bf16x2(v0, v1);
                }
        } else {
            #pragma unroll
            for (int mt = 0; mt < 4; ++mt)
                #pragma unroll
                for (int r = 0; r < 4; ++r) {
                    int samp = sbase + mt * 16 + q * 4 + r;
                    if (samp < nB) {
                        float v0 = softplus_log2(acc[mt][0][r] + bias0);
                        float v1 = softplus_log2(acc[mt][1][r] + bias1);
                        float* op = out + (size_t)samp * 32;
                        op[l16]      = fmaf(s_lin_ln2, v0, lb);
                        op[16 + l16] = fmaf(s_lin_ln2, v1, lb);
                    }
                }
        }
    }
}

extern "C" void kernel_launch(void* const* d_in, const int* in_sizes, int n_in,
                              void* d_out, int out_size, void* d_ws, size_t ws_size,
                              hipStream_t stream) {
    const float* x    = (const float*)d_in[0];
    const float* W1   = (const float*)d_in[1];
    const float* b1   = (const float*)d_in[2];
    const float* W2   = (const float*)d_in[3];
    const float* b2   = (const float*)d_in[4];
    const float* W3   = (const float*)d_in[5];
    const float* b3   = (const float*)d_in[6];
    const float* W4   = (const float*)d_in[7];
    const float* b4   = (const float*)d_in[8];
    const float* linW = (const float*)d_in[9];
    const float* linb = (const float*)d_in[10];
    float* out = (float*)d_out;

    const int nB   = in_sizes[0] / 12;
    const int grid = (nB + BLK - 1) / BLK;

    if (d_ws != nullptr && ws_size >= (size_t)WS_BYTES) {
        gnn_prep<<<1, 384, 0, stream>>>(W2, b2, W3, b3, W4, b4, linW, linb,
                                        (unsigned*)d_ws);
        gnn_mfma6<true><<<grid, BLK, 0, stream>>>(x, W1, b1, W2, b2, W3, b3, W4, b4,
                                                  linW, linb, (const unsigned*)d_ws,
                                                  out, nB);
    } else {
        gnn_mfma6<false><<<grid, BLK, 0, stream>>>(x, W1, b1, W2, b2, W3, b3, W4, b4,
                                                   linW, linb, nullptr, out, nB);
    }
}

// Round 4
// 195.569 us; speedup vs baseline: 1.0101x; 1.0005x over previous
//
#include <hip/hip_runtime.h>
#include <math.h>

// GNN_2826088481036 — R8 (= R7 resubmitted; R7 bench was an infra failure,
// "MI355X container failed twice" — no kernel signal).
// R6 with __launch_bounds__(256,4) on the main kernel.
// R6 post-mortem: hoisting ~550 VALU ops/lane to the prep kernel moved dur by
// only -1.9us -> main kernel is latency-bound, not VALU-bound. With u[32] gone
// and B-frag split in d_ws, live state ~110 VGPRs fits the 128-reg budget for
// 4 waves/SIMD (was 3). Occupancy is the knob that divides exposed HBM/LDS
// latency. No math changes (absmax must stay 0.00390625).

#define BLK 256
#define RS  20   // LDS row stride (dwords): mult of 4 (16B rows), 20%32 spreads banks

#define LOG2E 1.44269504088896340736f
#define LN2   0.69314718055994530942f

using short8 = __attribute__((ext_vector_type(8))) short;  // 8 bf16 A/B frag
using f32x4  = __attribute__((ext_vector_type(4))) float;  // C/D frag

__device__ __forceinline__ short8 as_s8(uint4 u) { return __builtin_bit_cast(short8, u); }

// RNE bf16 of a float, as low 16 bits (inputs here are never NaN)
__device__ __forceinline__ unsigned bf16_rne(float a) {
    unsigned u = __float_as_uint(a);
    return (u + 0x7fffu + ((u >> 16) & 1u)) >> 16;
}
__device__ __forceinline__ unsigned pack_bf16x2(float lo, float hi) {
    return bf16_rne(lo) | (bf16_rne(hi) << 16);
}

// u = log2(1 + 2^t)  ==  log2e * softplus(t/log2e); 3 instr, 2 transcendental
__device__ __forceinline__ float softplus_log2(float t) {
    return __builtin_amdgcn_logf(1.0f + __builtin_amdgcn_exp2f(t));
}

// ---- ws layout (dwords) ----
// [0, 3072)    : B-frag tables, uint4 index ((L*2+nt)*2 + h)*64 + lane, h=0 hi, h=1 lo
// [3072, 3168) : LOG2E * bL[f]   at 3072 + L*32 + f
// [3168]       : s_lin_ln2 = (linW[0]+linW[1]+linW[2]) * LN2
// [3169]       : lb = linb[0]
#define WS_DWORDS 3172
#define WS_BYTES  (WS_DWORDS * 4)

__global__ void gnn_prep(
    const float* __restrict__ W2, const float* __restrict__ b2,
    const float* __restrict__ W3, const float* __restrict__ b3,
    const float* __restrict__ W4, const float* __restrict__ b4,
    const float* __restrict__ linW, const float* __restrict__ linb,
    unsigned* __restrict__ ws)
{
    const int t = threadIdx.x;                 // 384 threads, 1 block
    const float* Ws[3] = { W2, W3, W4 };
    const float* bs[3] = { b2, b3, b4 };

    if (t < 384) {
        const int L    = t >> 7;               // layer 0..2
        const int nt   = (t >> 6) & 1;
        const int lane = t & 63;
        const int q    = lane >> 4;
        const int l16  = lane & 15;
        const float* __restrict__ W = Ws[L];
        unsigned hid[4], lod[4];
        #pragma unroll
        for (int d = 0; d < 4; ++d) {
            // permuted K: kappa=2d+e (+q*8) -> feature (q*4+d) + 16*e
            float w0 = W[(q * 4 + d) * 32      + nt * 16 + l16];
            float w1 = W[(q * 4 + d + 16) * 32 + nt * 16 + l16];
            unsigned h0 = bf16_rne(w0), h1 = bf16_rne(w1);
            float w0h = __uint_as_float(h0 << 16);
            float w1h = __uint_as_float(h1 << 16);
            hid[d] = h0 | (h1 << 16);
            lod[d] = pack_bf16x2(w0 - w0h, w1 - w1h);
        }
        uint4* o = (uint4*)ws;
        o[((L * 2 + nt) * 2 + 0) * 64 + lane] = make_uint4(hid[0], hid[1], hid[2], hid[3]);
        o[((L * 2 + nt) * 2 + 1) * 64 + lane] = make_uint4(lod[0], lod[1], lod[2], lod[3]);
    }
    if (t < 96) {
        const int L = t >> 5, f = t & 31;
        ((float*)ws)[3072 + t] = LOG2E * bs[L][f];
    }
    if (t == 96) ((float*)ws)[3168] = (linW[0] + linW[1] + linW[2]) * LN2;
    if (t == 97) ((float*)ws)[3169] = linb[0];
}

template<bool USE_WS>
__global__ __launch_bounds__(BLK, 4) void gnn_mfma8(
    const float* __restrict__ x,
    const float* __restrict__ W1, const float* __restrict__ b1,
    const float* __restrict__ W2, const float* __restrict__ b2,
    const float* __restrict__ W3, const float* __restrict__ b3,
    const float* __restrict__ W4, const float* __restrict__ b4,
    const float* __restrict__ linW, const float* __restrict__ linb,
    const unsigned* __restrict__ ws,
    float* __restrict__ out, int nB)
{
    __shared__ unsigned lds[4 * 64 * RS];          // 20,480 B

    const int tid  = threadIdx.x;
    const int wid  = tid >> 6;
    const int lane = tid & 63;
    const int q    = lane >> 4;    // k-chunk selector (A/B), row-quad (C)
    const int l16  = lane & 15;    // row (A) / col (B,C)

    unsigned* myLds = lds + wid * (64 * RS);
    const int sbase = blockIdx.x * BLK + wid * 64;

    // ---------------- layer 1 (K=4, VALU, t-domain) ----------------
    const int b0 = sbase + lane;
    float xm0 = 0.f, xm1 = 0.f, xm2 = 0.f, xm3 = 0.f;
    if (b0 < nB) {
        const float4* xp = (const float4*)(x + (size_t)b0 * 12);
        float4 n0 = xp[0], n1 = xp[1], n2 = xp[2];
        const float k = LOG2E / 3.0f;              // fold mean and log2e
        xm0 = (n0.x + n1.x + n2.x) * k;
        xm1 = (n0.y + n1.y + n2.y) * k;
        xm2 = (n0.z + n1.z + n2.z) * k;
        xm3 = (n0.w + n1.w + n2.w) * k;
    }
    {
        // own row: dword p = [sp(feat p+16) | sp(feat p)]; pack pair on the fly
        uint4* rowp = (uint4*)(myLds + lane * RS);
        #pragma unroll
        for (int d = 0; d < 4; ++d) {
            uint4 row;
            #pragma unroll
            for (int j = 0; j < 4; ++j) {
                const int f = 4 * d + j;
                float t0 = LOG2E * b1[f];                 // uniform -> scalar pipe
                t0 = fmaf(xm0, W1[f],       t0);
                t0 = fmaf(xm1, W1[32 + f],  t0);
                t0 = fmaf(xm2, W1[64 + f],  t0);
                t0 = fmaf(xm3, W1[96 + f],  t0);
                float t1 = LOG2E * b1[16 + f];
                t1 = fmaf(xm0, W1[16 + f],  t1);
                t1 = fmaf(xm1, W1[48 + f],  t1);
                t1 = fmaf(xm2, W1[80 + f],  t1);
                t1 = fmaf(xm3, W1[112 + f], t1);
                (&row.x)[j] = pack_bf16x2(softplus_log2(t0), softplus_log2(t1));
            }
            rowp[d] = row;
        }
    }

    const float* Ws[3] = { W2, W3, W4 };
    const float* bs[3] = { b2, b3, b4 };

    float s_lin_ln2, lb;
    if constexpr (USE_WS) {
        s_lin_ln2 = ((const float*)ws)[3168];
        lb        = ((const float*)ws)[3169];
    } else {
        s_lin_ln2 = (linW[0] + linW[1] + linW[2]) * LN2;
        lb        = linb[0];
    }

    // ---------------- layers 2..4 via MFMA ----------------
    #pragma unroll
    for (int layer = 0; layer < 3; ++layer) {
        // B frags, permuted K: kappa=2d+e (+q*8) -> feature (q*4+d) + 16*e
        uint4 bhi[2], blo[2];
        float bias0, bias1;
        if constexpr (USE_WS) {
            const uint4* wtab = (const uint4*)ws;
            #pragma unroll
            for (int nt = 0; nt < 2; ++nt) {
                bhi[nt] = wtab[((layer * 2 + nt) * 2 + 0) * 64 + lane];
                blo[nt] = wtab[((layer * 2 + nt) * 2 + 1) * 64 + lane];
            }
            bias0 = ((const float*)ws)[3072 + layer * 32 + l16];
            bias1 = ((const float*)ws)[3072 + layer * 32 + 16 + l16];
        } else {
            const float* __restrict__ W  = Ws[layer];
            const float* __restrict__ bL = bs[layer];
            #pragma unroll
            for (int nt = 0; nt < 2; ++nt) {
                #pragma unroll
                for (int d = 0; d < 4; ++d) {
                    float w0 = W[(q * 4 + d) * 32      + nt * 16 + l16];
                    float w1 = W[(q * 4 + d + 16) * 32 + nt * 16 + l16];
                    unsigned h0 = bf16_rne(w0), h1 = bf16_rne(w1);
                    float w0h = __uint_as_float(h0 << 16);
                    float w1h = __uint_as_float(h1 << 16);
                    (&bhi[nt].x)[d] = h0 | (h1 << 16);
                    (&blo[nt].x)[d] = pack_bf16x2(w0 - w0h, w1 - w1h);
                }
            }
            bias0 = LOG2E * bL[l16];
            bias1 = LOG2E * bL[16 + l16];
        }

        // A frags: one aligned ds_read_b128 per mt (row mt*16+l16, dwords q*4..q*4+3)
        uint4 afr[4];
        #pragma unroll
        for (int mt = 0; mt < 4; ++mt)
            afr[mt] = *(const uint4*)(myLds + (mt * 16 + l16) * RS + q * 4);

        // 16 MFMAs: acc = A*Bhi + A*Blo
        f32x4 acc[4][2];
        #pragma unroll
        for (int mt = 0; mt < 4; ++mt)
            #pragma unroll
            for (int nt = 0; nt < 2; ++nt) {
                f32x4 c = { 0.f, 0.f, 0.f, 0.f };
                c = __builtin_amdgcn_mfma_f32_16x16x32_bf16(as_s8(afr[mt]), as_s8(blo[nt]), c, 0, 0, 0);
                c = __builtin_amdgcn_mfma_f32_16x16x32_bf16(as_s8(afr[mt]), as_s8(bhi[nt]), c, 0, 0, 0);
                acc[mt][nt] = c;
            }

        if (layer < 2) {
            // softplus + pack pair (cols l16 / l16+16) + one ds_write per (mt,r)
            #pragma unroll
            for (int mt = 0; mt < 4; ++mt)
                #pragma unroll
                for (int r = 0; r < 4; ++r) {
                    float v0 = softplus_log2(acc[mt][0][r] + bias0);
                    float v1 = softplus_log2(acc[mt][1][r] + bias1);
                    myLds[(mt * 16 + q * 4 + r) * RS + l16] = pack_bf16x2(v0, v1);
                }
        } else {
            #pragma unroll
            for (int mt = 0; mt < 4; ++mt)
                #pragma unroll
                for (int r = 0; r < 4; ++r) {
                    int samp = sbase + mt * 16 + q * 4 + r;
                    if (samp < nB) {
                        float v0 = softplus_log2(acc[mt][0][r] + bias0);
                        float v1 = softplus_log2(acc[mt][1][r] + bias1);
                        float* op = out + (size_t)samp * 32;
                        op[l16]      = fmaf(s_lin_ln2, v0, lb);
                        op[16 + l16] = fmaf(s_lin_ln2, v1, lb);
                    }
                }
        }
    }
}

extern "C" void kernel_launch(void* const* d_in, const int* in_sizes, int n_in,
                              void* d_out, int out_size, void* d_ws, size_t ws_size,
                              hipStream_t stream) {
    const float* x    = (const float*)d_in[0];
    const float* W1   = (const float*)d_in[1];
    const float* b1   = (const float*)d_in[2];
    const float* W2   = (const float*)d_in[3];
    const float* b2   = (const float*)d_in[4];
    const float* W3   = (const float*)d_in[5];
    const float* b3   = (const float*)d_in[6];
    const float* W4   = (const float*)d_in[7];
    const float* b4   = (const float*)d_in[8];
    const float* linW = (const float*)d_in[9];
    const float* linb = (const float*)d_in[10];
    float* out = (float*)d_out;

    const int nB   = in_sizes[0] / 12;
    const int grid = (nB + BLK - 1) / BLK;

    if (d_ws != nullptr && ws_size >= (size_t)WS_BYTES) {
        gnn_prep<<<1, 384, 0, stream>>>(W2, b2, W3, b3, W4, b4, linW, linb,
                                        (unsigned*)d_ws);
        gnn_mfma8<true><<<grid, BLK, 0, stream>>>(x, W1, b1, W2, b2, W3, b3, W4, b4,
                                                  linW, linb, (const unsigned*)d_ws,
                                                  out, nB);
    } else {
        gnn_mfma8<false><<<grid, BLK, 0, stream>>>(x, W1, b1, W2, b2, W3, b3, W4, b4,
                                                   linW, linb, nullptr, out, nB);
    }
}

// Round 5
// 193.715 us; speedup vs baseline: 1.0198x; 1.0096x over previous
//
#include <hip/hip_runtime.h>
#include <math.h>

// GNN_2826088481036 — R9: R8 + coalesced output epilogue.
// R6 (VALU hoist) and R8 (occupancy 3->4) were both null -> kernel is not
// VALU- or occupancy-bound. Remaining candidate: store path (32 scattered
// per-sample-checked dword stores/wave). R9 stages final f32 results in LDS
// (layer tile is dead by then; LDS 20->32 KB/block, still 4 blocks/CU) and
// emits 8 coalesced dwordx4 stores/wave (16B/lane). nB%64==0 -> active waves
// are full -> fast path drops bounds checks; tail waves keep old path.
// Null result here => kernel is at the 176MB traffic floor => roofline.

#define BLK 256
#define RS  20   // LDS row stride (dwords) for layer tiles

#define LOG2E 1.44269504088896340736f
#define LN2   0.69314718055994530942f

using short8 = __attribute__((ext_vector_type(8))) short;  // 8 bf16 A/B frag
using f32x4  = __attribute__((ext_vector_type(4))) float;  // C/D frag

__device__ __forceinline__ short8 as_s8(uint4 u) { return __builtin_bit_cast(short8, u); }

// RNE bf16 of a float, as low 16 bits (inputs here are never NaN)
__device__ __forceinline__ unsigned bf16_rne(float a) {
    unsigned u = __float_as_uint(a);
    return (u + 0x7fffu + ((u >> 16) & 1u)) >> 16;
}
__device__ __forceinline__ unsigned pack_bf16x2(float lo, float hi) {
    return bf16_rne(lo) | (bf16_rne(hi) << 16);
}

// u = log2(1 + 2^t)  ==  log2e * softplus(t/log2e); 3 instr, 2 transcendental
__device__ __forceinline__ float softplus_log2(float t) {
    return __builtin_amdgcn_logf(1.0f + __builtin_amdgcn_exp2f(t));
}

// ---- ws layout (dwords) ----
// [0, 3072)    : B-frag tables, uint4 index ((L*2+nt)*2 + h)*64 + lane, h=0 hi, h=1 lo
// [3072, 3168) : LOG2E * bL[f]   at 3072 + L*32 + f
// [3168]       : s_lin_ln2 = (linW[0]+linW[1]+linW[2]) * LN2
// [3169]       : lb = linb[0]
#define WS_DWORDS 3172
#define WS_BYTES  (WS_DWORDS * 4)

__global__ void gnn_prep(
    const float* __restrict__ W2, const float* __restrict__ b2,
    const float* __restrict__ W3, const float* __restrict__ b3,
    const float* __restrict__ W4, const float* __restrict__ b4,
    const float* __restrict__ linW, const float* __restrict__ linb,
    unsigned* __restrict__ ws)
{
    const int t = threadIdx.x;                 // 384 threads, 1 block
    const float* Ws[3] = { W2, W3, W4 };
    const float* bs[3] = { b2, b3, b4 };

    if (t < 384) {
        const int L    = t >> 7;               // layer 0..2
        const int nt   = (t >> 6) & 1;
        const int lane = t & 63;
        const int q    = lane >> 4;
        const int l16  = lane & 15;
        const float* __restrict__ W = Ws[L];
        unsigned hid[4], lod[4];
        #pragma unroll
        for (int d = 0; d < 4; ++d) {
            // permuted K: kappa=2d+e (+q*8) -> feature (q*4+d) + 16*e
            float w0 = W[(q * 4 + d) * 32      + nt * 16 + l16];
            float w1 = W[(q * 4 + d + 16) * 32 + nt * 16 + l16];
            unsigned h0 = bf16_rne(w0), h1 = bf16_rne(w1);
            float w0h = __uint_as_float(h0 << 16);
            float w1h = __uint_as_float(h1 << 16);
            hid[d] = h0 | (h1 << 16);
            lod[d] = pack_bf16x2(w0 - w0h, w1 - w1h);
        }
        uint4* o = (uint4*)ws;
        o[((L * 2 + nt) * 2 + 0) * 64 + lane] = make_uint4(hid[0], hid[1], hid[2], hid[3]);
        o[((L * 2 + nt) * 2 + 1) * 64 + lane] = make_uint4(lod[0], lod[1], lod[2], lod[3]);
    }
    if (t < 96) {
        const int L = t >> 5, f = t & 31;
        ((float*)ws)[3072 + t] = LOG2E * bs[L][f];
    }
    if (t == 96) ((float*)ws)[3168] = (linW[0] + linW[1] + linW[2]) * LN2;
    if (t == 97) ((float*)ws)[3169] = linb[0];
}

template<bool USE_WS>
__global__ __launch_bounds__(BLK, 4) void gnn_mfma9(
    const float* __restrict__ x,
    const float* __restrict__ W1, const float* __restrict__ b1,
    const float* __restrict__ W2, const float* __restrict__ b2,
    const float* __restrict__ W3, const float* __restrict__ b3,
    const float* __restrict__ W4, const float* __restrict__ b4,
    const float* __restrict__ linW, const float* __restrict__ linb,
    const unsigned* __restrict__ ws,
    float* __restrict__ out, int nB)
{
    // 32 KB: per-wave 2048 dwords. Layer tiles use rows of RS=20 (1280 dwords);
    // the final epilogue reuses the full 2048 dwords as [64][32] f32 staging.
    __shared__ unsigned lds[4 * 2048];

    const int tid  = threadIdx.x;
    const int wid  = tid >> 6;
    const int lane = tid & 63;
    const int q    = lane >> 4;    // k-chunk selector (A/B), row-quad (C)
    const int l16  = lane & 15;    // row (A) / col (B,C)

    unsigned* myLds = lds + wid * 2048;
    const int sbase = blockIdx.x * BLK + wid * 64;

    // ---------------- layer 1 (K=4, VALU, t-domain) ----------------
    const int b0 = sbase + lane;
    float xm0 = 0.f, xm1 = 0.f, xm2 = 0.f, xm3 = 0.f;
    if (b0 < nB) {
        const float4* xp = (const float4*)(x + (size_t)b0 * 12);
        float4 n0 = xp[0], n1 = xp[1], n2 = xp[2];
        const float k = LOG2E / 3.0f;              // fold mean and log2e
        xm0 = (n0.x + n1.x + n2.x) * k;
        xm1 = (n0.y + n1.y + n2.y) * k;
        xm2 = (n0.z + n1.z + n2.z) * k;
        xm3 = (n0.w + n1.w + n2.w) * k;
    }
    {
        // own row: dword p = [sp(feat p+16) | sp(feat p)]; pack pair on the fly
        uint4* rowp = (uint4*)(myLds + lane * RS);
        #pragma unroll
        for (int d = 0; d < 4; ++d) {
            uint4 row;
            #pragma unroll
            for (int j = 0; j < 4; ++j) {
                const int f = 4 * d + j;
                float t0 = LOG2E * b1[f];                 // uniform -> scalar pipe
                t0 = fmaf(xm0, W1[f],       t0);
                t0 = fmaf(xm1, W1[32 + f],  t0);
                t0 = fmaf(xm2, W1[64 + f],  t0);
                t0 = fmaf(xm3, W1[96 + f],  t0);
                float t1 = LOG2E * b1[16 + f];
                t1 = fmaf(xm0, W1[16 + f],  t1);
                t1 = fmaf(xm1, W1[48 + f],  t1);
                t1 = fmaf(xm2, W1[80 + f],  t1);
                t1 = fmaf(xm3, W1[112 + f], t1);
                (&row.x)[j] = pack_bf16x2(softplus_log2(t0), softplus_log2(t1));
            }
            rowp[d] = row;
        }
    }

    const float* Ws[3] = { W2, W3, W4 };
    const float* bs[3] = { b2, b3, b4 };

    float s_lin_ln2, lb;
    if constexpr (USE_WS) {
        s_lin_ln2 = ((const float*)ws)[3168];
        lb        = ((const float*)ws)[3169];
    } else {
        s_lin_ln2 = (linW[0] + linW[1] + linW[2]) * LN2;
        lb        = linb[0];
    }

    // ---------------- layers 2..4 via MFMA ----------------
    #pragma unroll
    for (int layer = 0; layer < 3; ++layer) {
        // B frags, permuted K: kappa=2d+e (+q*8) -> feature (q*4+d) + 16*e
        uint4 bhi[2], blo[2];
        float bias0, bias1;
        if constexpr (USE_WS) {
            const uint4* wtab = (const uint4*)ws;
            #pragma unroll
            for (int nt = 0; nt < 2; ++nt) {
                bhi[nt] = wtab[((layer * 2 + nt) * 2 + 0) * 64 + lane];
                blo[nt] = wtab[((layer * 2 + nt) * 2 + 1) * 64 + lane];
            }
            bias0 = ((const float*)ws)[3072 + layer * 32 + l16];
            bias1 = ((const float*)ws)[3072 + layer * 32 + 16 + l16];
        } else {
            const float* __restrict__ W  = Ws[layer];
            const float* __restrict__ bL = bs[layer];
            #pragma unroll
            for (int nt = 0; nt < 2; ++nt) {
                #pragma unroll
                for (int d = 0; d < 4; ++d) {
                    float w0 = W[(q * 4 + d) * 32      + nt * 16 + l16];
                    float w1 = W[(q * 4 + d + 16) * 32 + nt * 16 + l16];
                    unsigned h0 = bf16_rne(w0), h1 = bf16_rne(w1);
                    float w0h = __uint_as_float(h0 << 16);
                    float w1h = __uint_as_float(h1 << 16);
                    (&bhi[nt].x)[d] = h0 | (h1 << 16);
                    (&blo[nt].x)[d] = pack_bf16x2(w0 - w0h, w1 - w1h);
                }
            }
            bias0 = LOG2E * bL[l16];
            bias1 = LOG2E * bL[16 + l16];
        }

        // A frags: one aligned ds_read_b128 per mt (row mt*16+l16, dwords q*4..q*4+3)
        uint4 afr[4];
        #pragma unroll
        for (int mt = 0; mt < 4; ++mt)
            afr[mt] = *(const uint4*)(myLds + (mt * 16 + l16) * RS + q * 4);

        // 16 MFMAs: acc = A*Bhi + A*Blo
        f32x4 acc[4][2];
        #pragma unroll
        for (int mt = 0; mt < 4; ++mt)
            #pragma unroll
            for (int nt = 0; nt < 2; ++nt) {
                f32x4 c = { 0.f, 0.f, 0.f, 0.f };
                c = __builtin_amdgcn_mfma_f32_16x16x32_bf16(as_s8(afr[mt]), as_s8(blo[nt]), c, 0, 0, 0);
                c = __builtin_amdgcn_mfma_f32_16x16x32_bf16(as_s8(afr[mt]), as_s8(bhi[nt]), c, 0, 0, 0);
                acc[mt][nt] = c;
            }

        if (layer < 2) {
            // softplus + pack pair (cols l16 / l16+16) + one ds_write per (mt,r)
            #pragma unroll
            for (int mt = 0; mt < 4; ++mt)
                #pragma unroll
                for (int r = 0; r < 4; ++r) {
                    float v0 = softplus_log2(acc[mt][0][r] + bias0);
                    float v1 = softplus_log2(acc[mt][1][r] + bias1);
                    myLds[(mt * 16 + q * 4 + r) * RS + l16] = pack_bf16x2(v0, v1);
                }
        } else {
            const bool fullWave = (sbase + 64 <= nB);   // wave-uniform
            if (fullWave) {
                // stage f32 results sample-major in LDS (layer tile is dead),
                // then 8 coalesced dwordx4 stores (16B/lane, 1KB/instr).
                float* stg = (float*)myLds;
                #pragma unroll
                for (int mt = 0; mt < 4; ++mt)
                    #pragma unroll
                    for (int r = 0; r < 4; ++r) {
                        const int s = mt * 16 + q * 4 + r;   // local sample 0..63
                        float v0 = softplus_log2(acc[mt][0][r] + bias0);
                        float v1 = softplus_log2(acc[mt][1][r] + bias1);
                        stg[s * 32 + l16]      = fmaf(s_lin_ln2, v0, lb);
                        stg[s * 32 + 16 + l16] = fmaf(s_lin_ln2, v1, lb);
                    }
                const float* sp = stg + lane * 4;
                float* op = out + (size_t)sbase * 32 + lane * 4;
                #pragma unroll
                for (int i = 0; i < 8; ++i)
                    *(float4*)(op + i * 256) = *(const float4*)(sp + i * 256);
            } else {
                #pragma unroll
                for (int mt = 0; mt < 4; ++mt)
                    #pragma unroll
                    for (int r = 0; r < 4; ++r) {
                        int samp = sbase + mt * 16 + q * 4 + r;
                        if (samp < nB) {
                            float v0 = softplus_log2(acc[mt][0][r] + bias0);
                            float v1 = softplus_log2(acc[mt][1][r] + bias1);
                            float* op = out + (size_t)samp * 32;
                            op[l16]      = fmaf(s_lin_ln2, v0, lb);
                            op[16 + l16] = fmaf(s_lin_ln2, v1, lb);
                        }
                    }
            }
        }
    }
}

extern "C" void kernel_launch(void* const* d_in, const int* in_sizes, int n_in,
                              void* d_out, int out_size, void* d_ws, size_t ws_size,
                              hipStream_t stream) {
    const float* x    = (const float*)d_in[0];
    const float* W1   = (const float*)d_in[1];
    const float* b1   = (const float*)d_in[2];
    const float* W2   = (const float*)d_in[3];
    const float* b2   = (const float*)d_in[4];
    const float* W3   = (const float*)d_in[5];
    const float* b3   = (const float*)d_in[6];
    const float* W4   = (const float*)d_in[7];
    const float* b4   = (const float*)d_in[8];
    const float* linW = (const float*)d_in[9];
    const float* linb = (const float*)d_in[10];
    float* out = (float*)d_out;

    const int nB   = in_sizes[0] / 12;
    const int grid = (nB + BLK - 1) / BLK;

    if (d_ws != nullptr && ws_size >= (size_t)WS_BYTES) {
        gnn_prep<<<1, 384, 0, stream>>>(W2, b2, W3, b3, W4, b4, linW, linb,
                                        (unsigned*)d_ws);
        gnn_mfma9<true><<<grid, BLK, 0, stream>>>(x, W1, b1, W2, b2, W3, b3, W4, b4,
                                                  linW, linb, (const unsigned*)d_ws,
                                                  out, nB);
    } else {
        gnn_mfma9<false><<<grid, BLK, 0, stream>>>(x, W1, b1, W2, b2, W3, b3, W4, b4,
                                                   linW, linb, nullptr, out, nB);
    }
}

// Round 7
// 190.184 us; speedup vs baseline: 1.0387x; 1.0186x over previous
//
#include <hip/hip_runtime.h>
#include <hip/hip_bf16.h>
#include <math.h>

// GNN_2826088481036 — R11: R10 with the pack fixed for this header version:
// __builtin_bit_cast(__hip_bfloat162) is rejected (not trivially copyable);
// use __bfloat16_as_ushort(__float2bfloat16(x)) raw-bits API instead. Still
// hardware cvt (RNE), no hand-written asm (R5 trap), no struct bit-cast
// (R10 trap). Prep kernel keeps bit-ops RNE (cold, self-consistent table).
// Ledger: R6 -1.9, R8 0, R9 -1.85; null here => all pipes at floor =>
// roofline next round.

#define BLK 256
#define RS  20   // LDS row stride (dwords) for layer tiles

#define LOG2E 1.44269504088896340736f
#define LN2   0.69314718055994530942f

using short8 = __attribute__((ext_vector_type(8))) short;  // 8 bf16 A/B frag
using f32x4  = __attribute__((ext_vector_type(4))) float;  // C/D frag

__device__ __forceinline__ short8 as_s8(uint4 u) { return __builtin_bit_cast(short8, u); }

// RNE bf16 of a float, as low 16 bits — bit-ops reference path (prep kernel)
__device__ __forceinline__ unsigned bf16_rne(float a) {
    unsigned u = __float_as_uint(a);
    return (u + 0x7fffu + ((u >> 16) & 1u)) >> 16;
}
__device__ __forceinline__ unsigned pack_bf16x2_bitops(float lo, float hi) {
    return bf16_rne(lo) | (bf16_rne(hi) << 16);
}

// hot-path pack: HW cvt (RNE) via documented raw-bits API; compiler may fuse
// the two converts into v_cvt_pk_bf16_f32.
__device__ __forceinline__ unsigned pack_bf16x2(float lo, float hi) {
    unsigned l = (unsigned)__bfloat16_as_ushort(__float2bfloat16(lo));
    unsigned h = (unsigned)__bfloat16_as_ushort(__float2bfloat16(hi));
    return l | (h << 16);
}

// u = log2(1 + 2^t)  ==  log2e * softplus(t/log2e); 3 instr, 2 transcendental
__device__ __forceinline__ float softplus_log2(float t) {
    return __builtin_amdgcn_logf(1.0f + __builtin_amdgcn_exp2f(t));
}

// ---- ws layout (dwords) ----
// [0, 3072)    : B-frag tables, uint4 index ((L*2+nt)*2 + h)*64 + lane, h=0 hi, h=1 lo
// [3072, 3168) : LOG2E * bL[f]   at 3072 + L*32 + f
// [3168]       : s_lin_ln2 = (linW[0]+linW[1]+linW[2]) * LN2
// [3169]       : lb = linb[0]
#define WS_DWORDS 3172
#define WS_BYTES  (WS_DWORDS * 4)

__global__ void gnn_prep(
    const float* __restrict__ W2, const float* __restrict__ b2,
    const float* __restrict__ W3, const float* __restrict__ b3,
    const float* __restrict__ W4, const float* __restrict__ b4,
    const float* __restrict__ linW, const float* __restrict__ linb,
    unsigned* __restrict__ ws)
{
    const int t = threadIdx.x;                 // 384 threads, 1 block
    const float* Ws[3] = { W2, W3, W4 };
    const float* bs[3] = { b2, b3, b4 };

    if (t < 384) {
        const int L    = t >> 7;               // layer 0..2
        const int nt   = (t >> 6) & 1;
        const int lane = t & 63;
        const int q    = lane >> 4;
        const int l16  = lane & 15;
        const float* __restrict__ W = Ws[L];
        unsigned hid[4], lod[4];
        #pragma unroll
        for (int d = 0; d < 4; ++d) {
            // permuted K: kappa=2d+e (+q*8) -> feature (q*4+d) + 16*e
            float w0 = W[(q * 4 + d) * 32      + nt * 16 + l16];
            float w1 = W[(q * 4 + d + 16) * 32 + nt * 16 + l16];
            unsigned h0 = bf16_rne(w0), h1 = bf16_rne(w1);
            float w0h = __uint_as_float(h0 << 16);
            float w1h = __uint_as_float(h1 << 16);
            hid[d] = h0 | (h1 << 16);
            lod[d] = pack_bf16x2_bitops(w0 - w0h, w1 - w1h);
        }
        uint4* o = (uint4*)ws;
        o[((L * 2 + nt) * 2 + 0) * 64 + lane] = make_uint4(hid[0], hid[1], hid[2], hid[3]);
        o[((L * 2 + nt) * 2 + 1) * 64 + lane] = make_uint4(lod[0], lod[1], lod[2], lod[3]);
    }
    if (t < 96) {
        const int L = t >> 5, f = t & 31;
        ((float*)ws)[3072 + t] = LOG2E * bs[L][f];
    }
    if (t == 96) ((float*)ws)[3168] = (linW[0] + linW[1] + linW[2]) * LN2;
    if (t == 97) ((float*)ws)[3169] = linb[0];
}

template<bool USE_WS>
__global__ __launch_bounds__(BLK, 4) void gnn_mfma11(
    const float* __restrict__ x,
    const float* __restrict__ W1, const float* __restrict__ b1,
    const float* __restrict__ W2, const float* __restrict__ b2,
    const float* __restrict__ W3, const float* __restrict__ b3,
    const float* __restrict__ W4, const float* __restrict__ b4,
    const float* __restrict__ linW, const float* __restrict__ linb,
    const unsigned* __restrict__ ws,
    float* __restrict__ out, int nB)
{
    // 32 KB: per-wave 2048 dwords. Layer tiles use rows of RS=20 (1280 dwords);
    // the final epilogue reuses the full 2048 dwords as [64][32] f32 staging.
    __shared__ unsigned lds[4 * 2048];

    const int tid  = threadIdx.x;
    const int wid  = tid >> 6;
    const int lane = tid & 63;
    const int q    = lane >> 4;    // k-chunk selector (A/B), row-quad (C)
    const int l16  = lane & 15;    // row (A) / col (B,C)

    unsigned* myLds = lds + wid * 2048;
    const int sbase = blockIdx.x * BLK + wid * 64;

    // ---------------- layer 1 (K=4, VALU, t-domain) ----------------
    const int b0 = sbase + lane;
    float xm0 = 0.f, xm1 = 0.f, xm2 = 0.f, xm3 = 0.f;
    if (b0 < nB) {
        const float4* xp = (const float4*)(x + (size_t)b0 * 12);
        float4 n0 = xp[0], n1 = xp[1], n2 = xp[2];
        const float k = LOG2E / 3.0f;              // fold mean and log2e
        xm0 = (n0.x + n1.x + n2.x) * k;
        xm1 = (n0.y + n1.y + n2.y) * k;
        xm2 = (n0.z + n1.z + n2.z) * k;
        xm3 = (n0.w + n1.w + n2.w) * k;
    }
    {
        // own row: dword p = [sp(feat p+16) | sp(feat p)]; pack pair on the fly
        uint4* rowp = (uint4*)(myLds + lane * RS);
        #pragma unroll
        for (int d = 0; d < 4; ++d) {
            uint4 row;
            #pragma unroll
            for (int j = 0; j < 4; ++j) {
                const int f = 4 * d + j;
                float t0 = LOG2E * b1[f];                 // uniform -> scalar pipe
                t0 = fmaf(xm0, W1[f],       t0);
                t0 = fmaf(xm1, W1[32 + f],  t0);
                t0 = fmaf(xm2, W1[64 + f],  t0);
                t0 = fmaf(xm3, W1[96 + f],  t0);
                float t1 = LOG2E * b1[16 + f];
                t1 = fmaf(xm0, W1[16 + f],  t1);
                t1 = fmaf(xm1, W1[48 + f],  t1);
                t1 = fmaf(xm2, W1[80 + f],  t1);
                t1 = fmaf(xm3, W1[112 + f], t1);
                (&row.x)[j] = pack_bf16x2(softplus_log2(t0), softplus_log2(t1));
            }
            rowp[d] = row;
        }
    }

    const float* Ws[3] = { W2, W3, W4 };
    const float* bs[3] = { b2, b3, b4 };

    float s_lin_ln2, lb;
    if constexpr (USE_WS) {
        s_lin_ln2 = ((const float*)ws)[3168];
        lb        = ((const float*)ws)[3169];
    } else {
        s_lin_ln2 = (linW[0] + linW[1] + linW[2]) * LN2;
        lb        = linb[0];
    }

    // ---------------- layers 2..4 via MFMA ----------------
    #pragma unroll
    for (int layer = 0; layer < 3; ++layer) {
        // B frags, permuted K: kappa=2d+e (+q*8) -> feature (q*4+d) + 16*e
        uint4 bhi[2], blo[2];
        float bias0, bias1;
        if constexpr (USE_WS) {
            const uint4* wtab = (const uint4*)ws;
            #pragma unroll
            for (int nt = 0; nt < 2; ++nt) {
                bhi[nt] = wtab[((layer * 2 + nt) * 2 + 0) * 64 + lane];
                blo[nt] = wtab[((layer * 2 + nt) * 2 + 1) * 64 + lane];
            }
            bias0 = ((const float*)ws)[3072 + layer * 32 + l16];
            bias1 = ((const float*)ws)[3072 + layer * 32 + 16 + l16];
        } else {
            const float* __restrict__ W  = Ws[layer];
            const float* __restrict__ bL = bs[layer];
            #pragma unroll
            for (int nt = 0; nt < 2; ++nt) {
                #pragma unroll
                for (int d = 0; d < 4; ++d) {
                    float w0 = W[(q * 4 + d) * 32      + nt * 16 + l16];
                    float w1 = W[(q * 4 + d + 16) * 32 + nt * 16 + l16];
                    unsigned h0 = bf16_rne(w0), h1 = bf16_rne(w1);
                    float w0h = __uint_as_float(h0 << 16);
                    float w1h = __uint_as_float(h1 << 16);
                    (&bhi[nt].x)[d] = h0 | (h1 << 16);
                    (&blo[nt].x)[d] = pack_bf16x2_bitops(w0 - w0h, w1 - w1h);
                }
            }
            bias0 = LOG2E * bL[l16];
            bias1 = LOG2E * bL[16 + l16];
        }

        // A frags: one aligned ds_read_b128 per mt (row mt*16+l16, dwords q*4..q*4+3)
        uint4 afr[4];
        #pragma unroll
        for (int mt = 0; mt < 4; ++mt)
            afr[mt] = *(const uint4*)(myLds + (mt * 16 + l16) * RS + q * 4);

        // 16 MFMAs: acc = A*Bhi + A*Blo
        f32x4 acc[4][2];
        #pragma unroll
        for (int mt = 0; mt < 4; ++mt)
            #pragma unroll
            for (int nt = 0; nt < 2; ++nt) {
                f32x4 c = { 0.f, 0.f, 0.f, 0.f };
                c = __builtin_amdgcn_mfma_f32_16x16x32_bf16(as_s8(afr[mt]), as_s8(blo[nt]), c, 0, 0, 0);
                c = __builtin_amdgcn_mfma_f32_16x16x32_bf16(as_s8(afr[mt]), as_s8(bhi[nt]), c, 0, 0, 0);
                acc[mt][nt] = c;
            }

        if (layer < 2) {
            // softplus + pack pair (cols l16 / l16+16) + one ds_write per (mt,r)
            #pragma unroll
            for (int mt = 0; mt < 4; ++mt)
                #pragma unroll
                for (int r = 0; r < 4; ++r) {
                    float v0 = softplus_log2(acc[mt][0][r] + bias0);
                    float v1 = softplus_log2(acc[mt][1][r] + bias1);
                    myLds[(mt * 16 + q * 4 + r) * RS + l16] = pack_bf16x2(v0, v1);
                }
        } else {
            const bool fullWave = (sbase + 64 <= nB);   // wave-uniform
            if (fullWave) {
                // stage f32 results sample-major in LDS (layer tile is dead),
                // then 8 coalesced dwordx4 stores (16B/lane, 1KB/instr).
                float* stg = (float*)myLds;
                #pragma unroll
                for (int mt = 0; mt < 4; ++mt)
                    #pragma unroll
                    for (int r = 0; r < 4; ++r) {
                        const int s = mt * 16 + q * 4 + r;   // local sample 0..63
                        float v0 = softplus_log2(acc[mt][0][r] + bias0);
                        float v1 = softplus_log2(acc[mt][1][r] + bias1);
                        stg[s * 32 + l16]      = fmaf(s_lin_ln2, v0, lb);
                        stg[s * 32 + 16 + l16] = fmaf(s_lin_ln2, v1, lb);
                    }
                const float* sp = stg + lane * 4;
                float* op = out + (size_t)sbase * 32 + lane * 4;
                #pragma unroll
                for (int i = 0; i < 8; ++i)
                    *(float4*)(op + i * 256) = *(const float4*)(sp + i * 256);
            } else {
                #pragma unroll
                for (int mt = 0; mt < 4; ++mt)
                    #pragma unroll
                    for (int r = 0; r < 4; ++r) {
                        int samp = sbase + mt * 16 + q * 4 + r;
                        if (samp < nB) {
                            float v0 = softplus_log2(acc[mt][0][r] + bias0);
                            float v1 = softplus_log2(acc[mt][1][r] + bias1);
                            float* op = out + (size_t)samp * 32;
                            op[l16]      = fmaf(s_lin_ln2, v0, lb);
                            op[16 + l16] = fmaf(s_lin_ln2, v1, lb);
                        }
                    }
            }
        }
    }
}

extern "C" void kernel_launch(void* const* d_in, const int* in_sizes, int n_in,
                              void* d_out, int out_size, void* d_ws, size_t ws_size,
                              hipStream_t stream) {
    const float* x    = (const float*)d_in[0];
    const float* W1   = (const float*)d_in[1];
    const float* b1   = (const float*)d_in[2];
    const float* W2   = (const float*)d_in[3];
    const float* b2   = (const float*)d_in[4];
    const float* W3   = (const float*)d_in[5];
    const float* b3   = (const float*)d_in[6];
    const float* W4   = (const float*)d_in[7];
    const float* b4   = (const float*)d_in[8];
    const float* linW = (const float*)d_in[9];
    const float* linb = (const float*)d_in[10];
    float* out = (float*)d_out;

    const int nB   = in_sizes[0] / 12;
    const int grid = (nB + BLK - 1) / BLK;

    if (d_ws != nullptr && ws_size >= (size_t)WS_BYTES) {
        gnn_prep<<<1, 384, 0, stream>>>(W2, b2, W3, b3, W4, b4, linW, linb,
                                        (unsigned*)d_ws);
        gnn_mfma11<true><<<grid, BLK, 0, stream>>>(x, W1, b1, W2, b2, W3, b3, W4, b4,
                                                   linW, linb, (const unsigned*)d_ws,
                                                   out, nB);
    } else {
        gnn_mfma11<false><<<grid, BLK, 0, stream>>>(x, W1, b1, W2, b2, W3, b3, W4, b4,
                                                    linW, linb, nullptr, out, nB);
    }
}